// Round 7
// baseline (315.871 us; speedup 1.0000x reference)
//
#include <hip/hip_runtime.h>

// MultiHeadAttention: B=4, T=2048, D=1024, H=16, HD=64, causal.
// cvt x->bf16; cvt+transpose W; m97-style async GEMM (QKV, XCD-striped);
// flash attention (BQ=128, 4 waves x 32 q, LPT heavy-first, LDS-staged DMA
// pipeline, no-max softmax, MFMA row-sum, direct epilogue); GEMM (proj).

typedef unsigned short u16;
typedef unsigned int u32;
typedef __attribute__((ext_vector_type(8))) short short8;   // 8 x bf16 MFMA operand
typedef __attribute__((ext_vector_type(4))) float f32x4;    // MFMA accumulator

#define MASKV (-1e30f)
#define SCLOG 0.1803368801111444f   // log2(e)/8  (folds 1/sqrt(64) into exp2 arg)

__device__ __forceinline__ u16 f2bf(float f) {
  union { float f; u32 u; } x; x.f = f;
  u32 r = x.u + 0x7FFFu + ((x.u >> 16) & 1u);   // RNE
  return (u16)(r >> 16);
}

__device__ __forceinline__ void async16(const u16* g, u16* l) {
  __builtin_amdgcn_global_load_lds((__attribute__((address_space(1))) void*)g,
                                   (__attribute__((address_space(3))) void*)l,
                                   16, 0, 0);
}

// ---------------- convert x: fp32 -> bf16 ----------------
__global__ void cvt_x_kernel(const float* __restrict__ x, u16* __restrict__ xb) {
  size_t i = ((size_t)blockIdx.x * 256 + threadIdx.x) * 4;
  float4 v = *(const float4*)(x + i);
  uint2 o;
  o.x = (u32)f2bf(v.x) | ((u32)f2bf(v.y) << 16);
  o.y = (u32)f2bf(v.z) | ((u32)f2bf(v.w) << 16);
  *(uint2*)(xb + i) = o;
}

// ------- convert + transpose weight: src[K][N] fp32 -> dst[N][K] bf16 -------
__global__ void cvt_tr_kernel(const float* __restrict__ src, u16* __restrict__ dst,
                              int K, int N) {
  __shared__ float tile[32][33];
  int n0 = blockIdx.x * 32, k0 = blockIdx.y * 32;
  int tx = threadIdx.x & 31, ty = threadIdx.x >> 5;
  #pragma unroll
  for (int r = ty; r < 32; r += 8)
    tile[r][tx] = src[(size_t)(k0 + r) * N + n0 + tx];
  __syncthreads();
  #pragma unroll
  for (int r = ty; r < 32; r += 8)
    dst[(size_t)(n0 + r) * K + k0 + tx] = f2bf(tile[tx][r]);
}

// ---------------- GEMM: C[M][N] = A[M][K] * Bt[N][K]^T + bias ----------------
// m97 pattern + XCD-aware remap: blocks with lid&7 == xcd form an 8-row M-stripe,
// so each XCD's L2 holds a 2 MB A working set instead of scattered tiles.
// Requires gridDim == (GX, 64).
template<bool BF16OUT, int GX>
__global__ __launch_bounds__(256) void gemm_bt(const u16* __restrict__ A,
                                               const u16* __restrict__ Bt,
                                               const float* __restrict__ bias,
                                               void* __restrict__ Cv, int N) {
  constexpr int K = 1024;
  __shared__ alignas(16) u16 As[128 * 32];
  __shared__ alignas(16) u16 Bs[128 * 32];
  const int t = threadIdx.x;
  const int w = t >> 6, lane = t & 63, quad = lane >> 4, l15 = lane & 15;
  const unsigned lid = blockIdx.y * GX + blockIdx.x;
  const unsigned xcd = lid & 7u, s = lid >> 3;
  const int m0 = ((xcd << 3) + s / GX) * 128;   // 8 consecutive M-rows per XCD
  const int n0 = (s % GX) * 128;
  const int wm = (w >> 1) * 64, wn = (w & 1) * 64;

  size_t gA[2], gB[2];
  int lds_st[2];
  #pragma unroll
  for (int ii = 0; ii < 2; ii++) {
    const int row = w * 32 + ii * 16 + (lane >> 2);
    const int db = (lane & 3) ^ (row & 3);
    gA[ii] = (size_t)(m0 + row) * K + db * 8;
    gB[ii] = (size_t)(n0 + row) * K + db * 8;
    lds_st[ii] = (w * 32 + ii * 16) * 32 + lane * 8;
  }
  const int fsw = (quad ^ (l15 & 3)) << 3;

  f32x4 acc[4][4];
  #pragma unroll
  for (int i = 0; i < 4; i++)
    #pragma unroll
    for (int j = 0; j < 4; j++)
      acc[i][j] = (f32x4){0.f, 0.f, 0.f, 0.f};

  for (int k0 = 0; k0 < K; k0 += 32) {
    __syncthreads();
    async16(A + gA[0] + k0, As + lds_st[0]);
    async16(A + gA[1] + k0, As + lds_st[1]);
    async16(Bt + gB[0] + k0, Bs + lds_st[0]);
    async16(Bt + gB[1] + k0, Bs + lds_st[1]);
    __syncthreads();
    short8 af[4], bf[4];
    #pragma unroll
    for (int i = 0; i < 4; i++)
      af[i] = *(const short8*)(As + (wm + i * 16 + l15) * 32 + fsw);
    #pragma unroll
    for (int j = 0; j < 4; j++)
      bf[j] = *(const short8*)(Bs + (wn + j * 16 + l15) * 32 + fsw);
    #pragma unroll
    for (int i = 0; i < 4; i++)
      #pragma unroll
      for (int j = 0; j < 4; j++)
        acc[i][j] = __builtin_amdgcn_mfma_f32_16x16x32_bf16(af[i], bf[j], acc[i][j], 0, 0, 0);
  }
  #pragma unroll
  for (int j = 0; j < 4; j++) {
    const int col = n0 + wn + j * 16 + l15;
    const float bv = bias[col];
    #pragma unroll
    for (int i = 0; i < 4; i++) {
      const int row = m0 + wm + i * 16 + quad * 4;
      #pragma unroll
      for (int r = 0; r < 4; r++) {
        float v = acc[i][j][r] + bv;
        if (BF16OUT) ((u16*)Cv)[(size_t)(row + r) * N + col] = f2bf(v);
        else         ((float*)Cv)[(size_t)(row + r) * N + col] = v;
      }
    }
  }
}

// ---------------- flash attention, causal ----------------
// Block = (bh, qt): 128 queries (4 waves x 32 q, 2 m-tiles), FULL k-range.
// Heavy q-tiles first (LPT over 1024 blocks). K async-DMA dbuf (source-permuted
// swizzle), V reg-prefetch + conflict-free transpose scatter, P via per-wave
// Gray-swizzled LDS, no-max softmax, MFMA row-sum l, direct store o/l.
__global__ __launch_bounds__(256) void flash_kernel(const u16* __restrict__ qkv,
                                                    u16* __restrict__ attn) {
  constexpr int T = 2048, N3 = 3072;
  __shared__ alignas(16) u16 Ks[2][64 * 64];
  __shared__ alignas(16) u16 VsT[2][64 * 64];
  __shared__ alignas(16) u16 Ps[4][32 * 64];
  const int t = threadIdx.x;
  const int w = t >> 6, lane = t & 63, quad = lane >> 4, l15 = lane & 15;
  const int bh = blockIdx.x, b = bh >> 4, h = bh & 15;
  const int qt = 15 - (int)blockIdx.y;          // heavy tiles first
  const int q0 = qt * 128;
  const int qw = q0 + w * 32;
  const int ktmax = 2 * qt + 1;

  const u16* base = qkv + (size_t)b * T * N3 + h * 64;
  const u16* Kg = base + 1024;
  const u16* Vg = base + 2048;

  // K async staging: wave w, 2 instrs, 8 keys x 128B each; source chunk permuted
  size_t gK[2];
  int ldsK[2];
  #pragma unroll
  for (int ii = 0; ii < 2; ii++) {
    const int key0 = w * 16 + ii * 8;
    const int key = key0 + (lane >> 3);
    const int db = ((lane & 7) ^ (key0 >> 3) ^ (lane >> 3)) & 7;
    gK[ii] = (size_t)key * N3 + db * 8;
    ldsK[ii] = key0 * 64 + lane * 8;
  }
  // V staging: lane loads V[vkey][vchunk*8..+7]
  const int vkey = w * 8 + (lane >> 3);
  const int vchunk = lane & 7;
  const size_t gV = (size_t)vkey * N3 + vchunk * 8;

  short8 onesf;
  #pragma unroll
  for (int j = 0; j < 8; j++) onesf[j] = (short)0x3F80;   // bf16 1.0

  // Q fragments: A[m=l15][k=quad*8+j], 2 m-tiles x 2 d-chunks
  short8 qf[2][2];
  #pragma unroll
  for (int mi = 0; mi < 2; mi++)
    #pragma unroll
    for (int kc = 0; kc < 2; kc++)
      qf[mi][kc] = *(const short8*)(base + (size_t)(qw + mi * 16 + l15) * N3 + kc * 32 + quad * 8);

  f32x4 o[2][4], lac[2];
  #pragma unroll
  for (int mi = 0; mi < 2; mi++) {
    lac[mi] = (f32x4){0.f, 0.f, 0.f, 0.f};
    #pragma unroll
    for (int dt = 0; dt < 4; dt++) o[mi][dt] = (f32x4){0.f, 0.f, 0.f, 0.f};
  }

  // preload tile 0
  async16(Kg + gK[0], &Ks[0][ldsK[0]]);
  async16(Kg + gK[1], &Ks[0][ldsK[1]]);
  {
    int4 vp0 = *(const int4*)(Vg + gV);
    int4 vp1 = *(const int4*)(Vg + gV + (size_t)32 * N3);
    union { int4 v; u16 u[8]; } uv;
    #pragma unroll
    for (int rd = 0; rd < 2; rd++) {
      uv.v = rd ? vp1 : vp0;
      const int kb = w + 4 * rd, ko = lane >> 3;
      #pragma unroll
      for (int j = 0; j < 8; j++)
        VsT[0][(vchunk * 8 + j) * 64 + (((kb ^ vchunk ^ j) & 7) << 3) + ko] = uv.u[j];
    }
  }

  int cur = 0;
  for (int kt = 0; kt <= ktmax; ++kt) {
    __syncthreads();   // drains K-DMA(kt); scatters + prior-iter reads visible
    const bool live = (kt * 64 <= qw + 31);   // wave-uniform
    const u16* Kc = Ks[cur];
    const u16* Vc = VsT[cur];
    u16* pw = Ps[w];
    short8 kf[4][2];
    if (live) {
      #pragma unroll
      for (int nt = 0; nt < 4; nt++) {
        const int kx = (nt * 2 + (l15 >> 3)) ^ (l15 & 7);
        #pragma unroll
        for (int ks = 0; ks < 2; ks++)
          kf[nt][ks] = *(const short8*)(Kc + (nt * 16 + l15) * 64 +
                                        ((((ks * 4 + quad) ^ kx) & 7) << 3));
      }
    }
    int4 vp0, vp1;
    if (kt < ktmax) {   // prefetch tile kt+1
      const size_t koff = (size_t)(kt + 1) * 64 * N3;
      async16(Kg + koff + gK[0], &Ks[cur ^ 1][ldsK[0]]);
      async16(Kg + koff + gK[1], &Ks[cur ^ 1][ldsK[1]]);
      vp0 = *(const int4*)(Vg + koff + gV);
      vp1 = *(const int4*)(Vg + koff + gV + (size_t)32 * N3);
    }
    if (live) {
      const bool needMask = (kt * 64 + 63 > qw);   // wave-uniform: diagonal iters only
      #pragma unroll
      for (int mi = 0; mi < 2; mi++) {
        f32x4 s[4];
        #pragma unroll
        for (int nt = 0; nt < 4; nt++) s[nt] = (f32x4){0.f, 0.f, 0.f, 0.f};
        #pragma unroll
        for (int nt = 0; nt < 4; nt++)
          #pragma unroll
          for (int kc = 0; kc < 2; kc++)
            s[nt] = __builtin_amdgcn_mfma_f32_16x16x32_bf16(qf[mi][kc], kf[nt][kc], s[nt], 0, 0, 0);
        if (needMask) {
          #pragma unroll
          for (int r = 0; r < 4; r++) {
            const int row = qw + mi * 16 + quad * 4 + r;
            #pragma unroll
            for (int nt = 0; nt < 4; nt++) {
              const int col = kt * 64 + nt * 16 + l15;
              if (col > row) s[nt][r] = MASKV;
            }
          }
        }
        // p = exp2(s*log2e/8) -> truncated bf16 -> per-wave Gray-swizzled LDS
        #pragma unroll
        for (int nt = 0; nt < 4; nt++) {
          const int lc = nt * 2 + (l15 >> 3);
          #pragma unroll
          for (int r = 0; r < 4; r++) {
            const int rl = mi * 16 + quad * 4 + r;
            const float p = __builtin_amdgcn_exp2f(s[nt][r] * SCLOG);
            union { float f; u32 u; } pc; pc.f = p;
            const int fp_ = (rl ^ (rl >> 1)) & 7;
            pw[rl * 64 + (((lc ^ fp_) & 7) << 3) + (l15 & 7)] = (u16)(pc.u >> 16);
          }
        }
      }
      // O += P V ; l += P 1   (Gray perm is identical for rows l15 and 16+l15)
      const int fpr = (l15 ^ (l15 >> 1)) & 7;
      #pragma unroll
      for (int ks = 0; ks < 2; ks++) {
        const int cb = ks * 4 + quad;
        const int ph = (cb ^ fpr) & 7;
        short8 pf0 = *(const short8*)(pw + l15 * 64 + (ph << 3));
        short8 pf1 = *(const short8*)(pw + (16 + l15) * 64 + (ph << 3));
        #pragma unroll
        for (int dt = 0; dt < 4; dt++) {
          const int vx = (dt * 2 + (l15 >> 3)) ^ (l15 & 7);
          short8 vf = *(const short8*)(Vc + (dt * 16 + l15) * 64 + (((cb ^ vx) & 7) << 3));
          o[0][dt] = __builtin_amdgcn_mfma_f32_16x16x32_bf16(pf0, vf, o[0][dt], 0, 0, 0);
          o[1][dt] = __builtin_amdgcn_mfma_f32_16x16x32_bf16(pf1, vf, o[1][dt], 0, 0, 0);
        }
        lac[0] = __builtin_amdgcn_mfma_f32_16x16x32_bf16(pf0, onesf, lac[0], 0, 0, 0);
        lac[1] = __builtin_amdgcn_mfma_f32_16x16x32_bf16(pf1, onesf, lac[1], 0, 0, 0);
      }
    }
    if (kt < ktmax) {  // transpose-scatter V(kt+1) into other buffer
      u16* Vn = (u16*)VsT[cur ^ 1];
      union { int4 v; u16 u[8]; } uv;
      #pragma unroll
      for (int rd = 0; rd < 2; rd++) {
        uv.v = rd ? vp1 : vp0;
        const int kb = w + 4 * rd, ko = lane >> 3;
        #pragma unroll
        for (int j = 0; j < 8; j++)
          Vn[(vchunk * 8 + j) * 64 + (((kb ^ vchunk ^ j) & 7) << 3) + ko] = uv.u[j];
      }
    }
    cur ^= 1;
  }

  // normalize + store bf16 [B*T][D]  (every lane's lac[mi][r] holds the row sum)
  #pragma unroll
  for (int mi = 0; mi < 2; mi++)
    #pragma unroll
    for (int r = 0; r < 4; r++) {
      const float invl = 1.0f / lac[mi][r];
      const int row = qw + mi * 16 + quad * 4 + r;
      const size_t off = (size_t)(b * T + row) * 1024 + h * 64;
      #pragma unroll
      for (int dt = 0; dt < 4; dt++)
        attn[off + dt * 16 + l15] = f2bf(o[mi][dt][r] * invl);
    }
}

extern "C" void kernel_launch(void* const* d_in, const int* in_sizes, int n_in,
                              void* d_out, int out_size, void* d_ws, size_t ws_size,
                              hipStream_t stream) {
  (void)in_sizes; (void)n_in; (void)out_size; (void)ws_size;
  const float* x     = (const float*)d_in[0];
  // d_in[1]: causal mask — statically tril, handled in-kernel
  const float* w_qkv = (const float*)d_in[2];
  const float* b_qkv = (const float*)d_in[3];
  const float* w_out = (const float*)d_in[4];
  const float* b_out = (const float*)d_in[5];
  float* out = (float*)d_out;

  char* ws = (char*)d_ws;
  u16* xb    = (u16*)(ws);                 // 8192*1024 bf16 = 16.78 MB (reused as attnb)
  u16* wqkvT = (u16*)(ws + 16777216);      // 3072*1024 bf16 =  6.29 MB
  u16* woutT = (u16*)(ws + 23068672);      // 1024*1024 bf16 =  2.10 MB
  u16* qkvb  = (u16*)(ws + 25165824);      // 8192*3072 bf16 = 50.33 MB
  u16* attnb = xb;                         // xb dead after QKV GEMM

  cvt_x_kernel<<<8192, 256, 0, stream>>>(x, xb);
  cvt_tr_kernel<<<dim3(96, 32), 256, 0, stream>>>(w_qkv, wqkvT, 1024, 3072);
  cvt_tr_kernel<<<dim3(32, 32), 256, 0, stream>>>(w_out, woutT, 1024, 1024);
  gemm_bt<true, 24><<<dim3(24, 64), 256, 0, stream>>>(xb, wqkvT, b_qkv, qkvb, 3072);
  flash_kernel<<<dim3(64, 16), 256, 0, stream>>>(qkvb, attnb);
  gemm_bt<false, 8><<<dim3(8, 64), 256, 0, stream>>>(attnb, woutT, b_out, out, 1024);
}